// Round 8
// baseline (33.866 us; speedup 1.0000x reference)
//
#include <hip/hip_runtime.h>

// ActorCriticMSECriterionAIC: masked MSE criterion.
// Inputs: seq [B,S] int32, value [B,S] f32, reward [B,S] f32 (B=65536, S=256).
// Outputs (3 f32): loss = sum(diff^2*mask)/sum(mask), mean(reward-value), mean(reward).
// mask[b,j] = 1 iff no zero among seq[b,0..j-1]  (count = first_zero+1, S if none).
//
// R7 post-mortem: hipLaunchCooperativeKernel silently no-ops under the
// harness's graph capture (out never written). Grid-wide fusion is thus
// unavailable (ticket+threadfence also proven racy across XCD L2s in R4).
// R8 = exact revert to R6 (32.5us, absmax 0):
//  - 2-kernel structure, interleaved rows, 4-row straight-line unroll.
//  - seq read in 64-elem chunks (1 dword/lane) with ballot early-exit:
//    avg ~266B/row instead of 1024B -> FETCH 98->74MB measured.
//  - reduce kernel delivers ~5.1 TB/s effective (~80% of the 6.3 TB/s copy
//    ceiling, on a 3-read-stream mix); VALU/LDS/occupancy all non-binding.

__global__ __launch_bounds__(256, 2) void ac_mse_reduce(
    const int* __restrict__ seq,
    const float* __restrict__ value,
    const float* __restrict__ reward,
    double* __restrict__ part,       // SoA [4][nb]
    int B, int nb) {

    const int S = 256;
    const int lane = threadIdx.x & 63;
    const int wv = threadIdx.x >> 6;
    const int wave = blockIdx.x * 4 + wv;
    const int T = nb * 4;                       // total waves

    double acc_sq = 0.0, acc_sd = 0.0, acc_sr = 0.0;
    int cnt = 0;

    const size_t step = (size_t)T * S;          // elements between my rows
    // seq: lane reads dword at (row, 64c + lane); v/r: float4 at (row, 4*lane)
    const int*   spl = seq + (size_t)wave * S + (size_t)lane;
    const float* vp  = value + (size_t)wave * S + (size_t)(lane * 4);
    const float* rp  = reward + (size_t)wave * S + (size_t)(lane * 4);

    // s0: my dword from seq elems [0..63]; sq: base of this row's seq (+lane)
    auto process = [&](int s0, const float4 v, const float4 r, const int* sq) {
        unsigned long long bal = __ballot(s0 == 0);
        int count;
        if (bal) {
            count = __ffsll(bal);               // first_zero + 1
        } else {
            count = S;
            // rare (3.8% of rows), wave-uniform chunk walk
            for (int c = 1; c < S / 64; ++c) {
                const int sc = sq[c * 64];      // sq already includes +lane
                const unsigned long long b2 = __ballot(sc == 0);
                if (b2) { count = c * 64 + (int)__ffsll(b2); break; }
            }
        }
        int m = count - 4 * lane;               // my masked-elem count (0..4)
        m = m < 0 ? 0 : (m > 4 ? 4 : m);

        const float d0 = r.x - v.x;
        const float d1 = r.y - v.y;
        const float d2 = r.z - v.z;
        const float d3 = r.w - v.w;
        float lsq = 0.0f;
        if (m > 0) lsq += d0 * d0;
        if (m > 1) lsq += d1 * d1;
        if (m > 2) lsq += d2 * d2;
        if (m > 3) lsq += d3 * d3;

        cnt += m;
        acc_sq += (double)lsq;
        acc_sd += (double)((d0 + d1) + (d2 + d3));
        acc_sr += (double)((r.x + r.y) + (r.z + r.w));
    };

    const int niter = (wave < B) ? ((B - 1 - wave) / T + 1) : 0;   // 8 at bench shape
    int k = 0;
    for (; k + 4 <= niter; k += 4) {
        // 12 loads issued straight-line (4 dword + 8 float4)
        const int    s0 = spl[0];
        const int    s1 = spl[step];
        const int    s2 = spl[2 * step];
        const int    s3 = spl[3 * step];
        const float4 v0 = *reinterpret_cast<const float4*>(vp);
        const float4 v1 = *reinterpret_cast<const float4*>(vp + step);
        const float4 v2 = *reinterpret_cast<const float4*>(vp + 2 * step);
        const float4 v3 = *reinterpret_cast<const float4*>(vp + 3 * step);
        const float4 r0 = *reinterpret_cast<const float4*>(rp);
        const float4 r1 = *reinterpret_cast<const float4*>(rp + step);
        const float4 r2 = *reinterpret_cast<const float4*>(rp + 2 * step);
        const float4 r3 = *reinterpret_cast<const float4*>(rp + 3 * step);
        process(s0, v0, r0, spl);
        process(s1, v1, r1, spl + step);
        process(s2, v2, r2, spl + 2 * step);
        process(s3, v3, r3, spl + 3 * step);
        spl += 4 * step; vp += 4 * step; rp += 4 * step;
    }
    for (; k < niter; ++k) {                    // generic-shape tail only
        const int    s0 = spl[0];
        const float4 v0 = *reinterpret_cast<const float4*>(vp);
        const float4 r0 = *reinterpret_cast<const float4*>(rp);
        process(s0, v0, r0, spl);
        spl += step; vp += step; rp += step;
    }

    // wave reduction (4 quantities)
    double acc_cnt = (double)cnt;
    #pragma unroll
    for (int off = 32; off > 0; off >>= 1) {
        acc_sq  += __shfl_down(acc_sq,  off);
        acc_cnt += __shfl_down(acc_cnt, off);
        acc_sd  += __shfl_down(acc_sd,  off);
        acc_sr  += __shfl_down(acc_sr,  off);
    }

    __shared__ double sm[4][4];
    if (lane == 0) {
        sm[0][wv] = acc_sq;
        sm[1][wv] = acc_cnt;
        sm[2][wv] = acc_sd;
        sm[3][wv] = acc_sr;
    }
    __syncthreads();
    if (threadIdx.x == 0) {
        part[0 * (size_t)nb + blockIdx.x] = sm[0][0] + sm[0][1] + sm[0][2] + sm[0][3];
        part[1 * (size_t)nb + blockIdx.x] = sm[1][0] + sm[1][1] + sm[1][2] + sm[1][3];
        part[2 * (size_t)nb + blockIdx.x] = sm[2][0] + sm[2][1] + sm[2][2] + sm[2][3];
        part[3 * (size_t)nb + blockIdx.x] = sm[3][0] + sm[3][1] + sm[3][2] + sm[3][3];
    }
}

// One block, 4 waves: wave c reduces component c over nb block-partials.
__global__ __launch_bounds__(256) void ac_mse_final(
    const double* __restrict__ part, float* __restrict__ out,
    int nb, double inv_n) {

    const int lane = threadIdx.x & 63;
    const int c = threadIdx.x >> 6;
    const double* p = part + (size_t)c * nb;

    double a0 = 0, a1 = 0, a2 = 0, a3 = 0;
    int b = lane;
    for (; b + 192 < nb; b += 256) {
        a0 += p[b]; a1 += p[b + 64]; a2 += p[b + 128]; a3 += p[b + 192];
    }
    for (; b < nb; b += 64) a0 += p[b];
    double a = (a0 + a1) + (a2 + a3);

    #pragma unroll
    for (int off = 32; off > 0; off >>= 1) a += __shfl_down(a, off);

    __shared__ double sm[4];
    if (lane == 0) sm[c] = a;
    __syncthreads();
    if (threadIdx.x == 0) {
        out[0] = (float)(sm[0] / sm[1]);            // loss
        out[1] = (float)(sm[2] * inv_n);            // mean(reward - value)
        out[2] = (float)(sm[3] * inv_n);            // mean(reward)
    }
}

extern "C" void kernel_launch(void* const* d_in, const int* in_sizes, int n_in,
                              void* d_out, int out_size, void* d_ws, size_t ws_size,
                              hipStream_t stream) {
    const int*   seq    = (const int*)d_in[0];
    const float* value  = (const float*)d_in[1];
    const float* reward = (const float*)d_in[2];
    float*  out = (float*)d_out;
    double* ws  = (double*)d_ws;

    const int S = 256;
    const long long total = (long long)in_sizes[0];
    const int B = (int)(total / S);

    int nb = 2048;   // 8192 waves -> 8 rows/wave at bench shape
    while ((size_t)nb * 4 * sizeof(double) > ws_size && nb > 1) nb >>= 1;

    ac_mse_reduce<<<nb, 256, 0, stream>>>(seq, value, reward, ws, B, nb);
    ac_mse_final<<<1, 256, 0, stream>>>(ws, out, nb, 1.0 / (double)total);
}